// Round 11
// baseline (245.037 us; speedup 1.0000x reference)
//
#include <hip/hip_runtime.h>

// FirstFrameBiasedEMA: y[0]=x[0]; y[t]=a*y[t-1]+(1-a)*x[t], a=0.9
// x: [B=16, T=4096, C=512] fp32.
//
// R13 = R12 resubmit (container infra failure x2, no kernel signal; code
// audited: bounds/asm/ledger/regs all safe — same failure class as R8 which
// passed unchanged as R9).
//
// R12: concurrency x pipeline. Service-rate model (measured): 2 waves/SIMD
// simple=2.86 TB/s (R2), 2 waves/SIMD + 32-deep asm pipeline=4.6 (R9, wall),
// 8 waves/SIMD simple=6.33 (R6, but 2x traffic amplification ate the win).
// Per-wave service appears capped (~2.2 GB/s/wave, in-order return), so the
// lever is MORE WAVES AT 1x TRAFFIC: split C as float2 (256 lanes/row) ->
// 1 row per 256-thread block -> 1024 blocks = 4 blocks/CU = 4 waves/SIMD,
// traffic unchanged (402 MB vector / 268 MB HBM). Keep R9's asm pipeline
// (dwordx2): 4096 waves x ~2.2 GB/s cap ~ 9 TB/s offered >> 6.3 ceiling.
// XCD swizzle dropped (R11: null). NT stores kept (harmless, mechanism-sound).
//
// Pipeline = R9 (proven absmax 0.0078): L=64, W=64 lookback (alpha^64 ~
// 1.2e-3), asm-volatile global_load_dwordx2 batches of 16, hand-counted
// s_waitcnt vmcnt(N) + sched_barrier(0) (rule #18). Ledger robust to
// within-window store/load interleave (drain targets = previous window's
// loads); NT stores count in vmcnt the same as plain stores (R11-proven).
//
// vmcnt ledger, chunk!=0 (8 batches of 16: 4 warmup, 4 stored):
//   L0 L1 | w16 -> L0 | C0, L2 | w16 -> L1 | C1, L3 | w16 -> L2 | C2, L4
//   | w16 -> L3 | C3, L5 | w16 -> L4 | C4+S4, L6 | w32 (newest=S4+L6) -> L5
//   | C5+S5, L7 | w32 (newest=S5+L7) -> L6 | C6+S6 | w16 (newest=S6) -> L7
//   | C7+S7.
// chunk==0: L0 L1 | w16 -> L0 | C0+S0, L2 | w32 -> L1 | C1+S1, L3 | w32 ->
//   L2 | C2+S2 | w16 -> L3 | C3+S3.

constexpr int T = 4096;
constexpr int C = 512;
constexpr int C2 = C / 2;     // float2 per row = 256
constexpr int L = 64;         // chunk length along T
constexpr int W = 64;         // lookback warm-up length
constexpr int CHUNKS = T / L; // 64
constexpr int NB = 16;        // loads per batch

typedef float vfloat2 __attribute__((ext_vector_type(2)));

#define WAITV(n) do { asm volatile("s_waitcnt vmcnt(" #n ")" ::: "memory"); \
                      __builtin_amdgcn_sched_barrier(0); } while (0)

__device__ __forceinline__ void loadB(const vfloat2* __restrict__ p, vfloat2 (&b)[NB]) {
    #pragma unroll
    for (int i = 0; i < NB; ++i) {
        const vfloat2* pi = p + (size_t)i * C2;
        asm volatile("global_load_dwordx2 %0, %1, off" : "=&v"(b[i]) : "v"(pi));
    }
}

__device__ __forceinline__ void emaB(vfloat2& yv, const vfloat2 (&b)[NB]) {
    #pragma unroll
    for (int i = 0; i < NB; ++i) yv = 0.9f * yv + 0.1f * b[i];
}

__device__ __forceinline__ void emaStoreB(vfloat2& yv, const vfloat2 (&b)[NB],
                                          vfloat2* __restrict__ yp) {
    #pragma unroll
    for (int i = 0; i < NB; ++i) {
        yv = 0.9f * yv + 0.1f * b[i];
        __builtin_nontemporal_store(yv, yp + (size_t)i * C2);
    }
}

__global__ __launch_bounds__(256, 4) void ema_chunk_kernel(
    const vfloat2* __restrict__ x, vfloat2* __restrict__ y)
{
    const int lane  = threadIdx.x;          // 0..255, float2 index in C
    const int row   = blockIdx.x;           // 0..B*CHUNKS-1 (one row per block)
    const int chunk = row & (CHUNKS - 1);
    const int b     = row >> 6;             // row / CHUNKS
    const int t0    = chunk * L;

    const size_t base = (size_t)b * T * C2 + lane;

    vfloat2 A[NB], Bb[NB];
    vfloat2 yv;

    if (chunk == 0) {
        const vfloat2* xp = x + base;
        vfloat2*       yp = y + base;
        loadB(xp, A);                    // L0
        loadB(xp + NB * C2, Bb);         // L1
        WAITV(16);                       // -> L0 done
        yv = A[0];
        __builtin_nontemporal_store(yv, yp);
        #pragma unroll
        for (int i = 1; i < NB; ++i) {   // C0+S0 (16 stores incl. elem 0)
            yv = 0.9f * yv + 0.1f * A[i];
            __builtin_nontemporal_store(yv, yp + (size_t)i * C2);
        }
        loadB(xp + 2 * NB * C2, A);      // L2
        WAITV(32);                       // newest 32 = S0+L2 -> L1 done
        emaStoreB(yv, Bb, yp + NB * C2);         // C1+S1
        loadB(xp + 3 * NB * C2, Bb);     // L3
        WAITV(32);                       // newest 32 = S1+L3 -> L2 done
        emaStoreB(yv, A, yp + 2 * NB * C2);      // C2+S2
        WAITV(16);                       // newest 16 = S2 -> L3 done
        emaStoreB(yv, Bb, yp + 3 * NB * C2);     // C3+S3
    } else {
        const vfloat2* xp = x + base + (size_t)(t0 - W) * C2;
        vfloat2*       yp = y + base + (size_t)t0 * C2;
        loadB(xp, A);                    // L0
        loadB(xp + NB * C2, Bb);         // L1
        WAITV(16);                       // -> L0 done
        yv = A[0];                       // pseudo first frame seed
        #pragma unroll
        for (int i = 1; i < NB; ++i) yv = 0.9f * yv + 0.1f * A[i];  // C0
        loadB(xp + 2 * NB * C2, A);      // L2
        WAITV(16);                       // out L1+L2=32 -> 16 => L1 done
        emaB(yv, Bb);                    // C1
        loadB(xp + 3 * NB * C2, Bb);     // L3
        WAITV(16);                       // -> L2 done
        emaB(yv, A);                     // C2
        loadB(xp + 4 * NB * C2, A);      // L4
        WAITV(16);                       // -> L3 done
        emaB(yv, Bb);                    // C3 — warm-up complete
        loadB(xp + 5 * NB * C2, Bb);     // L5
        WAITV(16);                       // -> L4 done
        emaStoreB(yv, A, yp);            // C4+S4
        loadB(xp + 6 * NB * C2, A);      // L6
        WAITV(32);                       // newest 32 = S4+L6 -> L5 done
        emaStoreB(yv, Bb, yp + NB * C2); // C5+S5
        loadB(xp + 7 * NB * C2, Bb);     // L7
        WAITV(32);                       // newest 32 = S5+L7 -> L6 done
        emaStoreB(yv, A, yp + 2 * NB * C2);  // C6+S6
        WAITV(16);                       // newest 16 = S6 -> L7 done
        emaStoreB(yv, Bb, yp + 3 * NB * C2); // C7+S7
    }
}

extern "C" void kernel_launch(void* const* d_in, const int* in_sizes, int n_in,
                              void* d_out, int out_size, void* d_ws, size_t ws_size,
                              hipStream_t stream) {
    const vfloat2* x = (const vfloat2*)d_in[0];
    vfloat2* y = (vfloat2*)d_out;
    const int B = in_sizes[0] / (T * C);  // 16

    const int rows = B * CHUNKS;          // 1024
    dim3 grid(rows);                      // 1 row per 256-thread block
    dim3 block(256);
    ema_chunk_kernel<<<grid, block, 0, stream>>>(x, y);
}